// Round 17
// baseline (142.550 us; speedup 1.0000x reference)
//
#include <hip/hip_runtime.h>
#include <math.h>

#define B_N 4096
#define C_N 100
#define D_N 384
#define EPSF 1e-12f
#define CT 5           // classes per tile
#define NT 20          // class tiles
#define NK (D_N / 16)  // 24 k-steps of 16 dims
#define KW (NK / 4)    // 6 k-steps per wave
#define RT 64          // rows per block (4 rows per thread)
#define NRT (B_N / RT) // 64 input rowtiles; rowtiles 64,65 are center rows
#define NBLK (NT * (NRT + 2))   // 1320 blocks

// tbl layout, CLASS-major (float4 units):
//   tbl4[(c*NK + k)*8 + seg]     = m2wc = -2 * w2 * center
//   tbl4[(c*NK + k)*8 + seg + 4] = w2
// d2(x, class c) = a2[c] + sum_d ( (w2*x + m2wc) * x )

// ---------------- prep: tbl, a2[c], present[c]; init apmax/anmin/cdminI/done
__global__ __launch_bounds__(128) void k_prep(const float* __restrict__ centers,
                                              const float* __restrict__ cw,
                                              const int* __restrict__ targets,
                                              float* __restrict__ tbl,
                                              float* __restrict__ a2,
                                              int* __restrict__ present,
                                              int* __restrict__ apmax,
                                              int* __restrict__ anmin,
                                              int* __restrict__ cdminI,
                                              int* __restrict__ done) {
    int c = blockIdx.x, t = threadIdx.x;
    __shared__ float sred[2];
    __shared__ int ps[2];

    float acc = 0.f;
    for (int d = t; d < D_N; d += 128) {
        float wv = exp2f(cw[c * D_N + d]);
        float ce = centers[c * D_N + d];
        float p  = wv * ce;
        int k = d >> 4, seg = (d >> 2) & 3, e = d & 3;
        int base = ((c * NK + k) * 8 + seg) * 4 + e;
        tbl[base]      = -2.f * p;   // m2wc
        tbl[base + 16] = wv;         // w2
        acc = fmaf(p, ce, acc);
    }
    for (int m = 1; m < 64; m <<= 1) acc += __shfl_xor(acc, m, 64);

    int pr = 0;
    for (int i = t; i < B_N; i += 128) pr |= (targets[i] == c) ? 1 : 0;
    pr = __any(pr) ? 1 : 0;

    if ((t & 63) == 0) { sred[t >> 6] = acc; ps[t >> 6] = pr; }

    int idx = c * 128 + t;                 // 12800 threads cover 4096 rows
    if (idx < B_N) {
        apmax[idx] = 0;                    // all g > 0
        anmin[idx] = 0x7F800000;           // +inf
    }
    if (c == 0) {
        if (t < C_N) cdminI[t] = 0x7F800000;
        if (t == 0) *done = 0;
    }

    __syncthreads();
    if (t == 0) { a2[c] = sred[0] + sred[1]; present[c] = ps[0] | ps[1]; }
}

// ---------------- main: block = 64 rows x 5 classes, 4 waves, K-split across waves.
// rowtile < NRT: input rows -> per-row atomicMax/Min(ap/an).
// rowtile >= NRT: center rows (clamped pad) -> atomicMin into cdminI.
// LAST finishing block performs the final loss reduction (no k_final node).
__global__ __launch_bounds__(256) void k_main(const float* __restrict__ inputs,
                                              const float* __restrict__ centers,
                                              const int* __restrict__ targets,
                                              const float* __restrict__ tbl,
                                              const float* __restrict__ a2,
                                              const int* __restrict__ present,
                                              int* __restrict__ apmax,
                                              int* __restrict__ anmin,
                                              int* __restrict__ cdminI,
                                              int* __restrict__ done,
                                              float* __restrict__ out) {
    __shared__ __align__(16) float4 tb[CT * NK * 8];   // 15360 B (aliased in epilogue)

    int tid  = threadIdx.x;
    int w    = tid >> 6;
    int l    = tid & 63;
    int slot = l & 15;
    int seg  = l >> 4;
    int ctile   = blockIdx.x;
    int rowtile = blockIdx.y;
    int c0 = ctile * CT;
    bool isc = (rowtile >= NRT);

    // ---- per-thread row pointers (4 rows: slot + 16*rr)
    const float *xp0, *xp1, *xp2, *xp3;
    if (!isc) {
        const float* base = inputs + (size_t)(rowtile * RT + slot) * D_N + seg * 4;
        xp0 = base;
        xp1 = base + 16 * D_N;
        xp2 = base + 32 * D_N;
        xp3 = base + 48 * D_N;
    } else {
        int cb = (rowtile - NRT) * RT + slot;
        int r0 = min(cb,      C_N - 1);
        int r1 = min(cb + 16, C_N - 1);
        int r2 = min(cb + 32, C_N - 1);
        int r3 = min(cb + 48, C_N - 1);
        xp0 = centers + (size_t)r0 * D_N + seg * 4;
        xp1 = centers + (size_t)r1 * D_N + seg * 4;
        xp2 = centers + (size_t)r2 * D_N + seg * 4;
        xp3 = centers + (size_t)r3 * D_N + seg * 4;
    }

    // prefetch kk=0 x rows (overlaps with staging below)
    int k0 = w * KW;
    float4 xr0 = *(const float4*)(xp0 + k0 * 16);
    float4 xr1 = *(const float4*)(xp1 + k0 * 16);
    float4 xr2 = *(const float4*)(xp2 + k0 * 16);
    float4 xr3 = *(const float4*)(xp3 + k0 * 16);

    // ---- stage class slice: CT*NK*8 = 960 float4s, contiguous in global
    {
        const float4* gsrc = (const float4*)tbl + (size_t)c0 * NK * 8;
        for (int q = tid; q < CT * NK * 8; q += 256) tb[q] = gsrc[q];
    }
    __syncthreads();

    float u[4][CT];
#pragma unroll
    for (int rr = 0; rr < 4; rr++)
#pragma unroll
        for (int j = 0; j < CT; j++) u[rr][j] = 0.f;

#pragma unroll 1
    for (int kk = 0; kk < KW; kk++) {
        int k = w * KW + kk;
        int kn = (kk + 1 < KW) ? (k + 1) : k;
        float4 xn0 = *(const float4*)(xp0 + kn * 16);
        float4 xn1 = *(const float4*)(xp1 + kn * 16);
        float4 xn2 = *(const float4*)(xp2 + kn * 16);
        float4 xn3 = *(const float4*)(xp3 + kn * 16);

        const float4* tk = tb + k * 8 + seg;
#pragma unroll
        for (int j = 0; j < CT; j++) {
            float4 m2 = tk[j * (NK * 8)];       // -2*w2*c
            float4 wv = tk[j * (NK * 8) + 4];   // w2
            float t;
            t = fmaf(wv.x, xr0.x, m2.x); u[0][j] = fmaf(t, xr0.x, u[0][j]);
            t = fmaf(wv.y, xr0.y, m2.y); u[0][j] = fmaf(t, xr0.y, u[0][j]);
            t = fmaf(wv.z, xr0.z, m2.z); u[0][j] = fmaf(t, xr0.z, u[0][j]);
            t = fmaf(wv.w, xr0.w, m2.w); u[0][j] = fmaf(t, xr0.w, u[0][j]);
            t = fmaf(wv.x, xr1.x, m2.x); u[1][j] = fmaf(t, xr1.x, u[1][j]);
            t = fmaf(wv.y, xr1.y, m2.y); u[1][j] = fmaf(t, xr1.y, u[1][j]);
            t = fmaf(wv.z, xr1.z, m2.z); u[1][j] = fmaf(t, xr1.z, u[1][j]);
            t = fmaf(wv.w, xr1.w, m2.w); u[1][j] = fmaf(t, xr1.w, u[1][j]);
            t = fmaf(wv.x, xr2.x, m2.x); u[2][j] = fmaf(t, xr2.x, u[2][j]);
            t = fmaf(wv.y, xr2.y, m2.y); u[2][j] = fmaf(t, xr2.y, u[2][j]);
            t = fmaf(wv.z, xr2.z, m2.z); u[2][j] = fmaf(t, xr2.z, u[2][j]);
            t = fmaf(wv.w, xr2.w, m2.w); u[2][j] = fmaf(t, xr2.w, u[2][j]);
            t = fmaf(wv.x, xr3.x, m2.x); u[3][j] = fmaf(t, xr3.x, u[3][j]);
            t = fmaf(wv.y, xr3.y, m2.y); u[3][j] = fmaf(t, xr3.y, u[3][j]);
            t = fmaf(wv.z, xr3.z, m2.z); u[3][j] = fmaf(t, xr3.z, u[3][j]);
            t = fmaf(wv.w, xr3.w, m2.w); u[3][j] = fmaf(t, xr3.w, u[3][j]);
        }
        xr0 = xn0; xr1 = xn1; xr2 = xn2; xr3 = xn3;
    }

    // ---- seg-reduce within wave (16-lane groups share (slot,rr))
#pragma unroll
    for (int rr = 0; rr < 4; rr++)
#pragma unroll
        for (int j = 0; j < CT; j++) {
            float a = u[rr][j];
            a += __shfl_xor(a, 16, 64);
            a += __shfl_xor(a, 32, 64);
            u[rr][j] = a;
        }

    // ---- cross-wave reduce: alias dead table LDS
    __syncthreads();   // all waves done reading tb
    float4* red4 = (float4*)tb;                     // [4w][CT][16slot] float4 (4 rr)
    float*  gbuf = (float*)tb + 4 * CT * RT;        // [CT][RT] floats
    if (l < 16) {
#pragma unroll
        for (int j = 0; j < CT; j++)
            red4[(w * CT + j) * 16 + slot] =
                make_float4(u[0][j], u[1][j], u[2][j], u[3][j]);
    }
    __syncthreads();

    // combine 4 wave-partials -> g for 320 (class,row) pairs
    const float* red = (const float*)red4;
#pragma unroll
    for (int part = 0; part < 2; part++) {
        int p = tid + part * 256;
        if (p < CT * RT) {
            int j = p >> 6, r = p & 63;
            int rr = r >> 4, sl = r & 15;
            int idx = (j * 16 + sl) * 4 + rr;
            float s = (red[(0 * CT * 16) * 4 + idx] + red[(1 * CT * 16) * 4 + idx])
                    + (red[(2 * CT * 16) * 4 + idx] + red[(3 * CT * 16) * 4 + idx]);
            gbuf[j * RT + r] = sqrtf(fmaxf(a2[c0 + j] + s, EPSF));
        }
    }
    __syncthreads();

    if (!isc) {
        // per-row ap/an -> device-scope atomics (int compare == float compare, g > 0;
        // min/max order-independent -> deterministic)
        if (tid < RT) {
            int row = rowtile * RT + tid;
            int ti  = targets[row];
            float ap = -1.f, an = INFINITY;
#pragma unroll
            for (int j = 0; j < CT; j++) {
                int c = c0 + j;
                float g = gbuf[j * RT + tid];
                if (c == ti) ap = g;
                else if (present[c]) an = fminf(an, g);
            }
            if (ap > 0.f) atomicMax(&apmax[row], __float_as_int(ap));
            atomicMin(&anmin[row], __float_as_int(an));
        }
    } else {
        // centers_dist partial: atomicMin into cdminI per class
        int jj = tid >> 4, sl = tid & 15;
        int rbase = (rowtile - NRT) * RT;     // 0 or 64
        if (jj < CT) {
            float m = INFINITY;
#pragma unroll
            for (int q = 0; q < 4; q++) {
                int r  = sl + 16 * q;
                int jg = rbase + r;
                float g = gbuf[jj * RT + r];
                if (jg < C_N && jg != c0 + jj) m = fminf(m, g);
            }
            m = fminf(m, __shfl_xor(m, 1, 64));
            m = fminf(m, __shfl_xor(m, 2, 64));
            m = fminf(m, __shfl_xor(m, 4, 64));
            m = fminf(m, __shfl_xor(m, 8, 64));
            if (sl == 0 && m < INFINITY) atomicMin(&cdminI[c0 + jj], __float_as_int(m));
        }
    }

    // ---- last-block-done final reduction (replaces k_final node)
    __threadfence();            // all my atomics globally visible
    __syncthreads();
    __shared__ int isLast;
    if (tid == 0) isLast = (atomicAdd(done, 1) == NBLK - 1);
    __syncthreads();
    if (isLast) {
        __threadfence();        // acquire: see all other blocks' atomics
        __shared__ float cd_s[C_N];
        __shared__ float sw[4];
        if (tid < C_N) cd_s[tid] = __int_as_float(cdminI[tid]);
        __syncthreads();

        float sum = 0.f;
        for (int row = tid; row < B_N; row += 256) {
            float ap = __int_as_float(apmax[row]);
            float an = __int_as_float(anmin[row]);
            float cc = cd_s[targets[row]];
            sum += (an >= cc) ? ap : (ap - an + cc);
        }
        for (int m = 1; m < 64; m <<= 1) sum += __shfl_xor(sum, m, 64);
        if (l == 0) sw[w] = sum;
        __syncthreads();
        if (tid == 0) out[0] = ((sw[0] + sw[1]) + (sw[2] + sw[3])) / (float)B_N;
    }
}

extern "C" void kernel_launch(void* const* d_in, const int* in_sizes, int n_in,
                              void* d_out, int out_size, void* d_ws, size_t ws_size,
                              hipStream_t stream) {
    const float* inputs  = (const float*)d_in[0];
    const float* centers = (const float*)d_in[1];
    const float* cw      = (const float*)d_in[2];
    const int*   targets = (const int*)d_in[3];
    (void)in_sizes; (void)n_in; (void)out_size; (void)ws_size;

    char* ws = (char*)d_ws;
    float* tbl     = (float*)(ws + 0);         // 307200 B
    int*   apmax   = (int*)  (ws + 307200);    // 16384 B
    int*   anmin   = (int*)  (ws + 323584);    // 16384 B
    float* a2      = (float*)(ws + 339968);    // 512 B
    int*   present = (int*)  (ws + 340480);    // 512 B
    int*   cdminI  = (int*)  (ws + 340992);    // 512 B
    int*   done    = (int*)  (ws + 341504);    // 4 B

    k_prep<<<C_N, 128, 0, stream>>>(centers, cw, targets, tbl, a2, present,
                                    apmax, anmin, cdminI, done);
    dim3 grid(NT, NRT + 2);   // 20 x 66 = 1320 blocks
    k_main<<<grid, 256, 0, stream>>>(inputs, centers, targets, tbl, a2, present,
                                     apmax, anmin, cdminI, done, (float*)d_out);
}

// Round 18
// 35.190 us; speedup vs baseline: 4.0509x; 4.0509x over previous
//
#include <hip/hip_runtime.h>
#include <math.h>

#define B_N 4096
#define C_N 100
#define D_N 384
#define EPSF 1e-12f
#define CT 5           // classes per tile
#define NT 20          // class tiles
#define NK (D_N / 16)  // 24 k-steps of 16 dims
#define KW (NK / 4)    // 6 k-steps per wave
#define RT 64          // rows per block-sub (4 rows per thread)
#define NRT (B_N / RT) // 64 input rowtiles; rowtiles 64,65 are center rows
#define SUBS 2         // rowtiles per block (table staged once)

// tbl layout, CLASS-major (float4 units):
//   tbl4[(c*NK + k)*8 + seg]     = m2wc = -2 * w2 * center
//   tbl4[(c*NK + k)*8 + seg + 4] = w2
// d2(x, class c) = a2[c] + sum_d ( (w2*x + m2wc) * x )

// ---------------- prep: tbl, a2[c], present[c]; init apmax/anmin (r14 version)
__global__ __launch_bounds__(128) void k_prep(const float* __restrict__ centers,
                                              const float* __restrict__ cw,
                                              const int* __restrict__ targets,
                                              float* __restrict__ tbl,
                                              float* __restrict__ a2,
                                              int* __restrict__ present,
                                              int* __restrict__ apmax,
                                              int* __restrict__ anmin) {
    int c = blockIdx.x, t = threadIdx.x;
    __shared__ float sred[2];
    __shared__ int ps[2];

    float acc = 0.f;
    for (int d = t; d < D_N; d += 128) {
        float wv = exp2f(cw[c * D_N + d]);
        float ce = centers[c * D_N + d];
        float p  = wv * ce;
        int k = d >> 4, seg = (d >> 2) & 3, e = d & 3;
        int base = ((c * NK + k) * 8 + seg) * 4 + e;
        tbl[base]      = -2.f * p;   // m2wc
        tbl[base + 16] = wv;         // w2
        acc = fmaf(p, ce, acc);
    }
    for (int m = 1; m < 64; m <<= 1) acc += __shfl_xor(acc, m, 64);

    int pr = 0;
    for (int i = t; i < B_N; i += 128) pr |= (targets[i] == c) ? 1 : 0;
    pr = __any(pr) ? 1 : 0;

    if ((t & 63) == 0) { sred[t >> 6] = acc; ps[t >> 6] = pr; }

    int idx = c * 128 + t;                 // 12800 threads cover 4096 rows
    if (idx < B_N) {
        apmax[idx] = 0;                    // all g > 0
        anmin[idx] = 0x7F800000;           // +inf
    }

    __syncthreads();
    if (t == 0) { a2[c] = sred[0] + sred[1]; present[c] = ps[0] | ps[1]; }
}

// ---------------- main: block = 5 classes x (SUBS x 64 rows); table staged ONCE.
// grid = 20 x 33. Block handles rowtiles 2*by and 2*by+1 with the same LDS table.
__global__ __launch_bounds__(256) void k_main(const float* __restrict__ inputs,
                                              const float* __restrict__ centers,
                                              const int* __restrict__ targets,
                                              const float* __restrict__ tbl,
                                              const float* __restrict__ a2,
                                              const int* __restrict__ present,
                                              int* __restrict__ apmax,
                                              int* __restrict__ anmin,
                                              float* __restrict__ cdmin) {
    __shared__ __align__(16) float4 tb[CT * NK * 8];     // 15360 B, live whole kernel
    __shared__ __align__(16) float4 red4[4 * CT * 16];   // 5120 B
    __shared__ float gbuf[CT * RT];                      // 1280 B

    int tid  = threadIdx.x;
    int w    = tid >> 6;
    int l    = tid & 63;
    int slot = l & 15;
    int seg  = l >> 4;
    int ctile = blockIdx.x;
    int c0 = ctile * CT;

    // ---- stage class slice once: CT*NK*8 = 960 float4s, contiguous in global
    {
        const float4* gsrc = (const float4*)tbl + (size_t)c0 * NK * 8;
        for (int q = tid; q < CT * NK * 8; q += 256) tb[q] = gsrc[q];
    }
    __syncthreads();

#pragma unroll 1
    for (int sub = 0; sub < SUBS; sub++) {
        int rowtile = blockIdx.y * SUBS + sub;
        bool isc = (rowtile >= NRT);

        // ---- per-thread row pointers (4 rows: slot + 16*rr)
        const float *xp0, *xp1, *xp2, *xp3;
        if (!isc) {
            const float* base = inputs + (size_t)(rowtile * RT + slot) * D_N + seg * 4;
            xp0 = base;
            xp1 = base + 16 * D_N;
            xp2 = base + 32 * D_N;
            xp3 = base + 48 * D_N;
        } else {
            int cb = (rowtile - NRT) * RT + slot;
            int r0 = min(cb,      C_N - 1);
            int r1 = min(cb + 16, C_N - 1);
            int r2 = min(cb + 32, C_N - 1);
            int r3 = min(cb + 48, C_N - 1);
            xp0 = centers + (size_t)r0 * D_N + seg * 4;
            xp1 = centers + (size_t)r1 * D_N + seg * 4;
            xp2 = centers + (size_t)r2 * D_N + seg * 4;
            xp3 = centers + (size_t)r3 * D_N + seg * 4;
        }

        int k0 = w * KW;
        float4 xr0 = *(const float4*)(xp0 + k0 * 16);
        float4 xr1 = *(const float4*)(xp1 + k0 * 16);
        float4 xr2 = *(const float4*)(xp2 + k0 * 16);
        float4 xr3 = *(const float4*)(xp3 + k0 * 16);

        float u[4][CT];
#pragma unroll
        for (int rr = 0; rr < 4; rr++)
#pragma unroll
            for (int j = 0; j < CT; j++) u[rr][j] = 0.f;

#pragma unroll 1
        for (int kk = 0; kk < KW; kk++) {
            int k = w * KW + kk;
            int kn = (kk + 1 < KW) ? (k + 1) : k;
            float4 xn0 = *(const float4*)(xp0 + kn * 16);
            float4 xn1 = *(const float4*)(xp1 + kn * 16);
            float4 xn2 = *(const float4*)(xp2 + kn * 16);
            float4 xn3 = *(const float4*)(xp3 + kn * 16);

            const float4* tk = tb + k * 8 + seg;
#pragma unroll
            for (int j = 0; j < CT; j++) {
                float4 m2 = tk[j * (NK * 8)];       // -2*w2*c
                float4 wv = tk[j * (NK * 8) + 4];   // w2
                float t;
                t = fmaf(wv.x, xr0.x, m2.x); u[0][j] = fmaf(t, xr0.x, u[0][j]);
                t = fmaf(wv.y, xr0.y, m2.y); u[0][j] = fmaf(t, xr0.y, u[0][j]);
                t = fmaf(wv.z, xr0.z, m2.z); u[0][j] = fmaf(t, xr0.z, u[0][j]);
                t = fmaf(wv.w, xr0.w, m2.w); u[0][j] = fmaf(t, xr0.w, u[0][j]);
                t = fmaf(wv.x, xr1.x, m2.x); u[1][j] = fmaf(t, xr1.x, u[1][j]);
                t = fmaf(wv.y, xr1.y, m2.y); u[1][j] = fmaf(t, xr1.y, u[1][j]);
                t = fmaf(wv.z, xr1.z, m2.z); u[1][j] = fmaf(t, xr1.z, u[1][j]);
                t = fmaf(wv.w, xr1.w, m2.w); u[1][j] = fmaf(t, xr1.w, u[1][j]);
                t = fmaf(wv.x, xr2.x, m2.x); u[2][j] = fmaf(t, xr2.x, u[2][j]);
                t = fmaf(wv.y, xr2.y, m2.y); u[2][j] = fmaf(t, xr2.y, u[2][j]);
                t = fmaf(wv.z, xr2.z, m2.z); u[2][j] = fmaf(t, xr2.z, u[2][j]);
                t = fmaf(wv.w, xr2.w, m2.w); u[2][j] = fmaf(t, xr2.w, u[2][j]);
                t = fmaf(wv.x, xr3.x, m2.x); u[3][j] = fmaf(t, xr3.x, u[3][j]);
                t = fmaf(wv.y, xr3.y, m2.y); u[3][j] = fmaf(t, xr3.y, u[3][j]);
                t = fmaf(wv.z, xr3.z, m2.z); u[3][j] = fmaf(t, xr3.z, u[3][j]);
                t = fmaf(wv.w, xr3.w, m2.w); u[3][j] = fmaf(t, xr3.w, u[3][j]);
            }
            xr0 = xn0; xr1 = xn1; xr2 = xn2; xr3 = xn3;
        }

        // ---- seg-reduce within wave (16-lane groups share (slot,rr))
#pragma unroll
        for (int rr = 0; rr < 4; rr++)
#pragma unroll
            for (int j = 0; j < CT; j++) {
                float a = u[rr][j];
                a += __shfl_xor(a, 16, 64);
                a += __shfl_xor(a, 32, 64);
                u[rr][j] = a;
            }

        // ---- cross-wave reduce via dedicated LDS (tb stays live)
        __syncthreads();   // prev sub's gbuf readers done; red4 safe to overwrite
        if (l < 16) {
#pragma unroll
            for (int j = 0; j < CT; j++)
                red4[(w * CT + j) * 16 + slot] =
                    make_float4(u[0][j], u[1][j], u[2][j], u[3][j]);
        }
        __syncthreads();

        // combine 4 wave-partials -> g for 320 (class,row) pairs
        const float* red = (const float*)red4;
#pragma unroll
        for (int part = 0; part < 2; part++) {
            int p = tid + part * 256;
            if (p < CT * RT) {
                int j = p >> 6, r = p & 63;
                int rr = r >> 4, sl = r & 15;
                int idx = (j * 16 + sl) * 4 + rr;
                float s = (red[(0 * CT * 16) * 4 + idx] + red[(1 * CT * 16) * 4 + idx])
                        + (red[(2 * CT * 16) * 4 + idx] + red[(3 * CT * 16) * 4 + idx]);
                gbuf[j * RT + r] = sqrtf(fmaxf(a2[c0 + j] + s, EPSF));
            }
        }
        __syncthreads();

        if (!isc) {
            // per-row ap/an -> atomics (int cmp == float cmp for g > 0;
            // min/max order-independent -> deterministic)
            if (tid < RT) {
                int row = rowtile * RT + tid;
                int ti  = targets[row];
                float ap = -1.f, an = INFINITY;
#pragma unroll
                for (int j = 0; j < CT; j++) {
                    int c = c0 + j;
                    float g = gbuf[j * RT + tid];
                    if (c == ti) ap = g;
                    else if (present[c]) an = fminf(an, g);
                }
                if (ap > 0.f) atomicMax(&apmax[row], __float_as_int(ap));
                atomicMin(&anmin[row], __float_as_int(an));
            }
        } else {
            // centers_dist partial: per class i = c0+jj, min over this sub's rows
            int jj = tid >> 4, sl = tid & 15;
            int rbase = (rowtile - NRT) * RT;     // 0 or 64
            if (jj < CT) {
                float m = INFINITY;
#pragma unroll
                for (int q = 0; q < 4; q++) {
                    int r  = sl + 16 * q;
                    int jg = rbase + r;
                    float g = gbuf[jj * RT + r];
                    if (jg < C_N && jg != c0 + jj) m = fminf(m, g);
                }
                m = fminf(m, __shfl_xor(m, 1, 64));
                m = fminf(m, __shfl_xor(m, 2, 64));
                m = fminf(m, __shfl_xor(m, 4, 64));
                m = fminf(m, __shfl_xor(m, 8, 64));
                if (sl == 0) cdmin[(c0 + jj) * 2 + (rbase >> 6)] = m;
            }
        }
    }
}

// ---------------- final: fold cdmin -> cdist, per-row loss from apmax/anmin, sum
__global__ __launch_bounds__(1024) void k_final(const int* __restrict__ apmax,
                                                const int* __restrict__ anmin,
                                                const float* __restrict__ cdmin,
                                                const int* __restrict__ targets,
                                                float* __restrict__ out) {
    int tid = threadIdx.x;
    __shared__ float cd_s[C_N];
    if (tid < C_N) cd_s[tid] = fminf(cdmin[tid * 2], cdmin[tid * 2 + 1]);
    __syncthreads();

    float sum = 0.f;
    for (int row = tid; row < B_N; row += 1024) {
        float ap = __int_as_float(apmax[row]);
        float an = __int_as_float(anmin[row]);
        float cc = cd_s[targets[row]];
        sum += (an >= cc) ? ap : (ap - an + cc);
    }
    for (int m = 1; m < 64; m <<= 1) sum += __shfl_xor(sum, m, 64);
    __shared__ float sw[16];
    if ((tid & 63) == 0) sw[tid >> 6] = sum;
    __syncthreads();
    if (tid < 64) {
        float v = (tid < 16) ? sw[tid] : 0.f;
        for (int m = 1; m < 16; m <<= 1) v += __shfl_xor(v, m, 64);
        if (tid == 0) out[0] = v / (float)B_N;
    }
}

extern "C" void kernel_launch(void* const* d_in, const int* in_sizes, int n_in,
                              void* d_out, int out_size, void* d_ws, size_t ws_size,
                              hipStream_t stream) {
    const float* inputs  = (const float*)d_in[0];
    const float* centers = (const float*)d_in[1];
    const float* cw      = (const float*)d_in[2];
    const int*   targets = (const int*)d_in[3];
    (void)in_sizes; (void)n_in; (void)out_size; (void)ws_size;

    char* ws = (char*)d_ws;
    float* tbl     = (float*)(ws + 0);         // 307200 B
    int*   apmax   = (int*)  (ws + 307200);    // 16384 B
    int*   anmin   = (int*)  (ws + 323584);    // 16384 B
    float* a2      = (float*)(ws + 339968);    // 512 B
    int*   present = (int*)  (ws + 340480);    // 512 B
    float* cdmin   = (float*)(ws + 340992);    // 800 B

    k_prep<<<C_N, 128, 0, stream>>>(centers, cw, targets, tbl, a2, present,
                                    apmax, anmin);
    dim3 grid(NT, (NRT + 2) / SUBS);   // 20 x 33 = 660 blocks
    k_main<<<grid, 256, 0, stream>>>(inputs, centers, targets, tbl, a2, present,
                                     apmax, anmin, cdmin);
    k_final<<<1, 1024, 0, stream>>>(apmax, anmin, cdmin, targets, (float*)d_out);
}